// Round 4
// baseline (303.897 us; speedup 1.0000x reference)
//
#include <hip/hip_runtime.h>

#define DEV __device__ __forceinline__

typedef float f32x4 __attribute__((ext_vector_type(4)));
typedef short short4v __attribute__((ext_vector_type(4)));
typedef short short8v __attribute__((ext_vector_type(8)));
typedef __bf16 bf16x8 __attribute__((ext_vector_type(8)));

DEV unsigned short f2bf(float f) {
  unsigned int u = __float_as_uint(f);
  u += 0x7fffu + ((u >> 16) & 1u);   // round-to-nearest-even
  return (unsigned short)(u >> 16);
}

DEV void async16(void* lds, const void* g) {
  __builtin_amdgcn_global_load_lds((const __attribute__((address_space(1))) void*)g,
                                   (__attribute__((address_space(3))) void*)lds, 16, 0, 0);
}

DEV void store_elem(float* C, long i, float v) { C[i] = v; }
DEV void store_elem(short* C, long i, float v) { C[i] = (short)f2bf(v); }

// ---------------- cast f32 -> bf16 (8 elems/thread) ----------------
__global__ void cast_bf16_kernel(const float* __restrict__ in, short* __restrict__ out) {
  long i = ((long)blockIdx.x * 256 + threadIdx.x) * 8;
  f32x4 a = *(const f32x4*)(in + i);
  f32x4 b = *(const f32x4*)(in + i + 4);
  short8v o;
#pragma unroll
  for (int j = 0; j < 4; ++j) { o[j] = (short)f2bf(a[j]); o[4 + j] = (short)f2bf(b[j]); }
  *(short8v*)(out + i) = o;
}

// ---------------- W [K=1024][N=1024] f32 -> Wt [N][K] bf16 ----------------
__global__ void transpose_cast_kernel(const float* __restrict__ W, short* __restrict__ Wt) {
  __shared__ float t[32][33];
  int n0 = blockIdx.x * 32, k0 = blockIdx.y * 32;
  int tx = threadIdx.x & 31, ty = threadIdx.x >> 5;
#pragma unroll
  for (int r = 0; r < 32; r += 8) t[ty + r][tx] = W[(long)(k0 + ty + r) * 1024 + n0 + tx];
  __syncthreads();
#pragma unroll
  for (int r = 0; r < 32; r += 8)
    Wt[(long)(n0 + ty + r) * 1024 + k0 + tx] = (short)f2bf(t[tx][ty + r]);
}

__global__ void concat2_kernel(const float* __restrict__ a, const float* __restrict__ b,
                               float* __restrict__ o) {
  int i = blockIdx.x * 256 + threadIdx.x;
  o[i] = (i < 1024) ? a[i] : b[i - 1024];
}

// =====================================================================
// 256x256 GEMM, BK=64, 8 waves (2Mx4N), per-wave 128x64, 16x16x32 bf16 MFMA.
// st_16x32 LDS swizzle: tile stored as [row/16][col/32] subtiles of 1KB;
// within a subtile, element (r,c) lives at col c^((r&8)?16:0). global_load_lds
// writes linearly, so the per-lane GLOBAL source is inverse-permuted
// (lane l sources col-chunk (l&3)^((l&32)?2:0)); ds_reads apply the same XOR.
// Pipeline: per K-tile 2 phases {12 ds_read_b128 -> lgkmcnt(0) -> 32 MFMA},
// STAGE(t+2) issued between a reads-done barrier and a publish barrier with
// counted vmcnt(8) (never 0 in the main loop).
// MODE: 0 plain, 1 = lower+diag tiles + fused column-stats, 2 = K cap (bm+1)*256.
// =====================================================================
template <typename CT, int MODE>
__global__ __launch_bounds__(512, 2) void gemm256(
    const short* __restrict__ A, const short* __restrict__ Bt, CT* __restrict__ C,
    int K, int lda, int ldbt, int ldc,
    long sA, long sBt, long sC,
    const float* __restrict__ bias_m, const float* __restrict__ bias_n, float scale,
    float* __restrict__ pm_out, float* __restrict__ ps_out)
{
  const int bn = blockIdx.x, bm = blockIdx.y, bz = blockIdx.z;
  if (MODE == 1 && bn > bm) return;
  const int kend = (MODE == 2) ? min(K, (bm + 1) * 256) : K;
  const int NT = kend >> 6;                       // BK=64 tiles (always even here)

  A += (long)bz * sA;  Bt += (long)bz * sBt;  C += (long)bz * sC;

  __shared__ __align__(16) short Abuf[2][16384];  // 2 x 256x64 bf16 = 2 x 32KB
  __shared__ __align__(16) short Bbuf[2][16384];  // total 128KB

  const int tid = threadIdx.x;
  const int wid = tid >> 6, lane = tid & 63;
  const int wm = wid >> 2, wn = wid & 3;
  const int fr = lane & 15, fq = lane >> 4;

  // staging decomposition: one gload_lds = one 1KB subtile (16 rows x 32 cols)
  const int lrow = lane >> 2;                               // row within subtile
  const int lcol = ((lane & 3) * 8) ^ ((lane & 32) ? 16 : 0); // inverse-swz col
  // read-side inner offset within a subtile (shorts)
  const int rd_in = fr * 32 + ((fq * 8) ^ ((fr & 8) ? 16 : 0));

  const short* pA[4];
  const short* pB[4];
#pragma unroll
  for (int s4 = 0; s4 < 4; ++s4) {
    int s = wid * 4 + s4;                                   // subtile id 0..31
    pA[s4] = A + (long)(bm * 256 + (s >> 1) * 16 + lrow) * lda + (s & 1) * 32 + lcol;
    pB[s4] = Bt + (long)(bn * 256 + (s >> 1) * 16 + lrow) * ldbt + (s & 1) * 32 + lcol;
  }

  auto STAGE = [&](int b, int t) {                          // 8 gload_lds / thread
    const int k0 = t << 6;
#pragma unroll
    for (int s4 = 0; s4 < 4; ++s4)
      async16(&Abuf[b][(wid * 4 + s4) * 512], pA[s4] + k0);
#pragma unroll
    for (int s4 = 0; s4 < 4; ++s4)
      async16(&Bbuf[b][(wid * 4 + s4) * 512], pB[s4] + k0);
  };

  f32x4 acc[8][4] = {};

  STAGE(0, 0);
  STAGE(1, 1);
  asm volatile("s_waitcnt vmcnt(8)" ::: "memory");          // tile 0 resident
  __builtin_amdgcn_s_barrier();

  auto body = [&](int b, int t) {
    const short* Ab_ = &Abuf[b][0];
    const short* Bb_ = &Bbuf[b][0];
    // ---- phase 1 : k-slice 0 ----
    bf16x8 a0[8], r0[4];
#pragma unroll
    for (int i = 0; i < 8; ++i)
      a0[i] = *(const bf16x8*)(Ab_ + ((wm * 8 + i) * 2 + 0) * 512 + rd_in);
#pragma unroll
    for (int j = 0; j < 4; ++j)
      r0[j] = *(const bf16x8*)(Bb_ + ((wn * 4 + j) * 2 + 0) * 512 + rd_in);
    asm volatile("s_waitcnt lgkmcnt(0)" ::: "memory");
    __builtin_amdgcn_sched_barrier(0);
    __builtin_amdgcn_s_setprio(1);
#pragma unroll
    for (int i = 0; i < 8; ++i)
#pragma unroll
      for (int j = 0; j < 4; ++j)
        acc[i][j] = __builtin_amdgcn_mfma_f32_16x16x32_bf16(a0[i], r0[j], acc[i][j], 0, 0, 0);
    __builtin_amdgcn_s_setprio(0);
    // ---- phase 2 : k-slice 1, with prefetch of tile t+2 into this buffer ----
    bf16x8 a1[8], r1[4];
#pragma unroll
    for (int i = 0; i < 8; ++i)
      a1[i] = *(const bf16x8*)(Ab_ + ((wm * 8 + i) * 2 + 1) * 512 + rd_in);
#pragma unroll
    for (int j = 0; j < 4; ++j)
      r1[j] = *(const bf16x8*)(Bb_ + ((wn * 4 + j) * 2 + 1) * 512 + rd_in);
    asm volatile("s_waitcnt lgkmcnt(0)" ::: "memory");
    __builtin_amdgcn_sched_barrier(0);
    __builtin_amdgcn_s_barrier();                 // all waves done reading buf b
    if (t + 2 < NT) {
      STAGE(b, t + 2);
      asm volatile("s_waitcnt vmcnt(8)" ::: "memory");  // own t+1 loads done
    } else {
      asm volatile("s_waitcnt vmcnt(0)" ::: "memory");  // tail drain
    }
    __builtin_amdgcn_s_barrier();                 // t+1 published to all waves
    __builtin_amdgcn_s_setprio(1);
#pragma unroll
    for (int i = 0; i < 8; ++i)
#pragma unroll
      for (int j = 0; j < 4; ++j)
        acc[i][j] = __builtin_amdgcn_mfma_f32_16x16x32_bf16(a1[i], r1[j], acc[i][j], 0, 0, 0);
    __builtin_amdgcn_s_setprio(0);
  };

  for (int t = 0; t < NT; t += 2) { body(0, t); body(1, t + 1); }

  // ---- epilogue: C write ----
#pragma unroll
  for (int i = 0; i < 8; ++i) {
#pragma unroll
    for (int r = 0; r < 4; ++r) {
      int row = bm * 256 + wm * 128 + i * 16 + fq * 4 + r;
      float bmv = bias_m ? bias_m[row] : 0.f;
#pragma unroll
      for (int j = 0; j < 4; ++j) {
        int col = bn * 256 + wn * 64 + j * 16 + fr;
        float bnv = bias_n ? bias_n[col] : 0.f;
        store_elem(C, (long)row * ldc + col, acc[i][j][r] * scale + bmv + bnv);
      }
    }
  }

  // ---- fused column (query-axis) stats over this block's 256 rows ----
  if constexpr (MODE == 1) {
    float* smax = (float*)&Abuf[0][0];            // [2][256]
    float* ssum = smax + 512;
    const int rowg0 = bm * 256 + wm * 128 + fq * 4;
#pragma unroll
    for (int j = 0; j < 4; ++j) {
      const int col = bn * 256 + wn * 64 + j * 16 + fr;
      float m = -1e30f;
#pragma unroll
      for (int i = 0; i < 8; ++i)
#pragma unroll
        for (int r = 0; r < 4; ++r) {
          float v = acc[i][j][r] * scale;
          m = (rowg0 + i * 16 + r >= col) ? fmaxf(m, v) : m;
        }
      m = fmaxf(m, __shfl_xor(m, 16));
      m = fmaxf(m, __shfl_xor(m, 32));
      float s = 0.f;
#pragma unroll
      for (int i = 0; i < 8; ++i)
#pragma unroll
        for (int r = 0; r < 4; ++r) {
          float v = acc[i][j][r] * scale;
          s += (rowg0 + i * 16 + r >= col) ? __expf(v - m) : 0.f;
        }
      s += __shfl_xor(s, 16);
      s += __shfl_xor(s, 32);
      if (fq == 0) {
        smax[wm * 256 + wn * 64 + j * 16 + fr] = m;
        ssum[wm * 256 + wn * 64 + j * 16 + fr] = s;
      }
    }
    __syncthreads();
    if (tid < 256) {
      float m0 = smax[tid], m1 = smax[256 + tid];
      float s0 = ssum[tid], s1 = ssum[256 + tid];
      float M = fmaxf(m0, m1);
      float S2 = (m0 > -1e29f ? s0 * __expf(m0 - M) : 0.f)
               + (m1 > -1e29f ? s1 * __expf(m1 - M) : 0.f);
      long o = ((long)bz * 8 + bm) * 2048 + bn * 256 + tid;
      pm_out[o] = M;
      ps_out[o] = S2;
    }
  }
}

// combine 8 row-chunk (256-row) partials per column; chunks < c/256 never written.
__global__ void colstats_combine(const float* __restrict__ pmax, const float* __restrict__ psum,
                                 float* __restrict__ cmax, float* __restrict__ cinv) {
  const int bz = blockIdx.y;
  const int c = blockIdx.x * 256 + threadIdx.x;
  const int ch0 = c >> 8;
  float M = -1e30f;
  for (int ch = ch0; ch < 8; ++ch) M = fmaxf(M, pmax[((long)bz * 8 + ch) * 2048 + c]);
  float Ssum = 0.f;
  for (int ch = ch0; ch < 8; ++ch) {
    float m = pmax[((long)bz * 8 + ch) * 2048 + c];
    float s = psum[((long)bz * 8 + ch) * 2048 + c];
    Ssum += (m > -1e29f) ? s * __expf(m - M) : 0.f;
  }
  cmax[(long)bz * 2048 + c] = M;
  cinv[(long)bz * 2048 + c] = 1.f / Ssum;
}

// P = (q>=c) ? exp(S-M[c])*Rinv[c] : 0 (bf16); only c < ((q>>8)+1)*256 is live.
__global__ void sm_normalize(const float* __restrict__ S, const float* __restrict__ cmax,
                             const float* __restrict__ cinv, short* __restrict__ P) {
  const int bz = blockIdx.y;
  const int q = blockIdx.x;
  const int climit = ((q >> 8) + 1) << 8;
  const float* Sr = S + ((long)bz * 2048 + q) * 2048;
  short* Pr = P + ((long)bz * 2048 + q) * 2048;
  const float* Mb = cmax + (long)bz * 2048;
  const float* Rb = cinv + (long)bz * 2048;
  for (int c = threadIdx.x * 4; c < climit; c += 1024) {
    f32x4 sv = *(const f32x4*)(Sr + c);
    f32x4 mv = *(const f32x4*)(Mb + c);
    f32x4 rv = *(const f32x4*)(Rb + c);
    short4v o;
#pragma unroll
    for (int j = 0; j < 4; ++j) {
      float p = (q >= c + j) ? __expf(sv[j] - mv[j]) * rv[j] : 0.f;
      o[j] = (short)f2bf(p);
    }
    *(short4v*)(Pr + c) = o;
  }
}

// ---------------- host side ----------------
extern "C" void kernel_launch(void* const* d_in, const int* in_sizes, int n_in,
                              void* d_out, int out_size, void* d_ws, size_t ws_size,
                              hipStream_t stream) {
  const float* x  = (const float*)d_in[0];
  const float* Wq = (const float*)d_in[1];
  const float* bq = (const float*)d_in[2];
  const float* Wk = (const float*)d_in[3];
  const float* bk = (const float*)d_in[4];
  const float* Wv = (const float*)d_in[5];
  const float* bv = (const float*)d_in[6];
  float* out = (float*)d_out;

  const size_t SZ_XB  = 8192ull * 1024 * 2;
  const size_t SZ_WQK = 2048ull * 1024 * 2;
  const size_t SZ_WT  = 1024ull * 1024 * 2;
  const size_t SZ_QK  = 8192ull * 2048 * 2;
  const size_t SZ_VT  = 1024ull * 8192 * 2;
  const size_t N_PMAX = 4ull * 8 * 2048;
  const size_t N_CMAX = 4ull * 2048;
  const size_t SZ_STATS = (N_PMAX * 2 + N_CMAX * 2 + 2048) * 4;
  const size_t SZ_S1 = 2048ull * 2048 * 4;
  const size_t SZ_P1 = 2048ull * 2048 * 2;

  char* p = (char*)d_ws;
  short* xb   = (short*)p; p += SZ_XB;
  short* wqkt = (short*)p; p += SZ_WQK;
  short* wvt  = (short*)p; p += SZ_WT;
  short* qkb  = (short*)p; p += SZ_QK;
  short* vt   = (short*)p; p += SZ_VT;
  float* pmax = (float*)p;
  float* psum = pmax + N_PMAX;
  float* cmax = psum + N_PMAX;
  float* cinv = cmax + N_CMAX;
  float* bqk  = cinv + N_CMAX;
  p += SZ_STATS;
  size_t fixed = (size_t)(p - (char*)d_ws);
  int nbuf = (ws_size >= fixed + 4 * (SZ_S1 + SZ_P1)) ? 4 : 1;
  float* S = (float*)p; p += (size_t)nbuf * SZ_S1;
  short* P = (short*)p;

  cast_bf16_kernel<<<dim3(4096), dim3(256), 0, stream>>>(x, xb);
  transpose_cast_kernel<<<dim3(32, 32), dim3(256), 0, stream>>>(Wq, wqkt);
  transpose_cast_kernel<<<dim3(32, 32), dim3(256), 0, stream>>>(Wk, wqkt + 1024 * 1024);
  transpose_cast_kernel<<<dim3(32, 32), dim3(256), 0, stream>>>(Wv, wvt);
  concat2_kernel<<<dim3(8), dim3(256), 0, stream>>>(bq, bk, bqk);

  // QK fused projection: C[8192][2048] = xb @ [Wq;Wk]^T + [bq;bk]
  gemm256<short, 0><<<dim3(8, 32, 1), dim3(512), 0, stream>>>(
      xb, wqkt, qkb, 1024, 1024, 1024, 2048, 0L, 0L, 0L, nullptr, bqk, 1.f,
      nullptr, nullptr);
  // Vt[d][s] = Wv^T x^T + bv
  gemm256<short, 0><<<dim3(32, 4, 1), dim3(512), 0, stream>>>(
      wvt, xb, vt, 1024, 1024, 1024, 8192, 0L, 0L, 0L, bv, nullptr, 1.f,
      nullptr, nullptr);

  const long QKSTR = 2048L * 2048;
  const long SSTR  = 2048L * 2048;
  const long OSTR  = 2048L * 1024;

  for (int b0 = 0; b0 < 4; b0 += nbuf) {
    // scores + fused stats: S[q][k] = Q.K^T/32, lower+diag 256-tiles only
    gemm256<float, 1><<<dim3(8, 8, nbuf), dim3(512), 0, stream>>>(
        qkb + (long)b0 * QKSTR, qkb + (long)b0 * QKSTR + 1024, S,
        1024, 2048, 2048, 2048, QKSTR, QKSTR, SSTR,
        nullptr, nullptr, 0.03125f, pmax, psum);
    colstats_combine<<<dim3(8, nbuf), dim3(256), 0, stream>>>(pmax, psum, cmax, cinv);
    sm_normalize<<<dim3(2048, nbuf), dim3(256), 0, stream>>>(S, cmax, cinv, P);
    // attn = P @ V, K capped at (bm+1)*256
    gemm256<float, 2><<<dim3(4, 8, nbuf), dim3(512), 0, stream>>>(
        P, vt + b0 * 2048, out + (long)b0 * OSTR, 2048, 2048, 8192, 1024,
        SSTR, 2048L, OSTR, nullptr, nullptr, 1.f, nullptr, nullptr);
  }
}

// Round 5
// 247.785 us; speedup vs baseline: 1.2265x; 1.2265x over previous
//
#include <hip/hip_runtime.h>

#define DEV __device__ __forceinline__

typedef float f32x4 __attribute__((ext_vector_type(4)));
typedef short short4v __attribute__((ext_vector_type(4)));
typedef short short8v __attribute__((ext_vector_type(8)));
typedef __bf16 bf16x8 __attribute__((ext_vector_type(8)));

DEV unsigned short f2bf(float f) {
  unsigned int u = __float_as_uint(f);
  u += 0x7fffu + ((u >> 16) & 1u);   // round-to-nearest-even
  return (unsigned short)(u >> 16);
}

DEV void async16(void* lds, const void* g) {
  __builtin_amdgcn_global_load_lds((const __attribute__((address_space(1))) void*)g,
                                   (__attribute__((address_space(3))) void*)lds, 16, 0, 0);
}

DEV void store_elem(float* C, long i, float v) { C[i] = v; }
DEV void store_elem(short* C, long i, float v) { C[i] = (short)f2bf(v); }

// ---------------- cast f32 -> bf16 (8 elems/thread) ----------------
__global__ void cast_bf16_kernel(const float* __restrict__ in, short* __restrict__ out) {
  long i = ((long)blockIdx.x * 256 + threadIdx.x) * 8;
  f32x4 a = *(const f32x4*)(in + i);
  f32x4 b = *(const f32x4*)(in + i + 4);
  short8v o;
#pragma unroll
  for (int j = 0; j < 4; ++j) { o[j] = (short)f2bf(a[j]); o[4 + j] = (short)f2bf(b[j]); }
  *(short8v*)(out + i) = o;
}

// ---------------- W [K=1024][N=1024] f32 -> Wt [N][K] bf16 ----------------
__global__ void transpose_cast_kernel(const float* __restrict__ W, short* __restrict__ Wt) {
  __shared__ float t[32][33];
  int n0 = blockIdx.x * 32, k0 = blockIdx.y * 32;
  int tx = threadIdx.x & 31, ty = threadIdx.x >> 5;
#pragma unroll
  for (int r = 0; r < 32; r += 8) t[ty + r][tx] = W[(long)(k0 + ty + r) * 1024 + n0 + tx];
  __syncthreads();
#pragma unroll
  for (int r = 0; r < 32; r += 8)
    Wt[(long)(n0 + ty + r) * 1024 + k0 + tx] = (short)f2bf(t[tx][ty + r]);
}

__global__ void concat2_kernel(const float* __restrict__ a, const float* __restrict__ b,
                               float* __restrict__ o) {
  int i = blockIdx.x * 256 + threadIdx.x;
  o[i] = (i < 1024) ? a[i] : b[i - 1024];
}

// ---------------- GEMM: C[M][N] = scale * A[M][K] @ Bt[N][K]^T (+bias) ----------------
// R2-proven 128x128 tile, BK=32, 4 waves (2x2), 4x4 16x16x32 bf16 MFMA.
// Double-buffered LDS + counted vmcnt(4).
// MODE: 0 plain 2D grid; 1 = compact 1D lower-triangle grid + fused column-stats.
template <typename CT, int MODE>
__global__ __launch_bounds__(256, 2) void gemm_bt(
    const short* __restrict__ A, const short* __restrict__ Bt, CT* __restrict__ C,
    int K, int lda, int ldbt, int ldc,
    long sA, long sBt, long sC,
    const float* __restrict__ bias_m, const float* __restrict__ bias_n, float scale,
    float* __restrict__ pm_out, float* __restrict__ ps_out)
{
  int bn, bm;
  if constexpr (MODE == 1) {
    int idx = blockIdx.x;
    bm = 0;
    while ((bm + 1) * (bm + 2) / 2 <= idx) ++bm;   // triangle-number decode
    bn = idx - bm * (bm + 1) / 2;                  // bn <= bm guaranteed
  } else {
    bn = blockIdx.x; bm = blockIdx.y;
  }
  const int bz = blockIdx.z;
  const int kend = K;

  A += (long)bz * sA;  Bt += (long)bz * sBt;  C += (long)bz * sC;

  __shared__ __align__(16) short As[2][128 * 32];
  __shared__ __align__(16) short Bs[2][128 * 32];

  const int tid = threadIdx.x;
  const int wid = tid >> 6, lane = tid & 63;
  const int wm = wid >> 1, wn = wid & 1;
  const int rC = lane >> 2;
  const int kB = (lane & 3) * 8;
  const int fr = lane & 15;
  const int fkB = (lane >> 4) * 16;

  const short* Ab = A + (long)bm * 128 * lda + (long)rC * lda + kB;
  const short* Bb = Bt + (long)bn * 128 * ldbt + (long)rC * ldbt + kB;

  f32x4 acc[4][4] = {};

  auto STAGE = [&](int b, int kk) {
#pragma unroll
    for (int j = 0; j < 2; ++j) {
      int chunk = j * 4 + wid;
      async16(&As[b][chunk * 512], Ab + (long)chunk * 16 * lda + kk);
    }
#pragma unroll
    for (int j = 0; j < 2; ++j) {
      int chunk = j * 4 + wid;
      async16(&Bs[b][chunk * 512], Bb + (long)chunk * 16 * ldbt + kk);
    }
  };

  STAGE(0, 0);
  int cur = 0;
  for (int kk = 0; kk < kend; kk += 32) {
    if (kk + 32 < kend) {
      STAGE(cur ^ 1, kk + 32);
      asm volatile("s_waitcnt vmcnt(4)" ::: "memory");
    } else {
      asm volatile("s_waitcnt vmcnt(0)" ::: "memory");
    }
    __builtin_amdgcn_s_barrier();
    __builtin_amdgcn_sched_barrier(0);

    bf16x8 af[4], bf_[4];
#pragma unroll
    for (int i = 0; i < 4; ++i)
      af[i] = *(const bf16x8*)((const char*)&As[cur][0] + (wm * 64 + i * 16 + fr) * 64 + fkB);
#pragma unroll
    for (int j = 0; j < 4; ++j)
      bf_[j] = *(const bf16x8*)((const char*)&Bs[cur][0] + (wn * 64 + j * 16 + fr) * 64 + fkB);
#pragma unroll
    for (int i = 0; i < 4; ++i)
#pragma unroll
      for (int j = 0; j < 4; ++j)
        acc[i][j] = __builtin_amdgcn_mfma_f32_16x16x32_bf16(af[i], bf_[j], acc[i][j], 0, 0, 0);
    __builtin_amdgcn_s_barrier();
    cur ^= 1;
  }

  const int fq = lane >> 4;
#pragma unroll
  for (int i = 0; i < 4; ++i) {
#pragma unroll
    for (int r = 0; r < 4; ++r) {
      int row = bm * 128 + wm * 64 + i * 16 + fq * 4 + r;
      float bmv = bias_m ? bias_m[row] : 0.f;
#pragma unroll
      for (int j = 0; j < 4; ++j) {
        int col = bn * 128 + wn * 64 + j * 16 + fr;
        float bnv = bias_n ? bias_n[col] : 0.f;
        store_elem(C, (long)row * ldc + col, acc[i][j][r] * scale + bmv + bnv);
      }
    }
  }

  if constexpr (MODE == 1) {
    // fused column (query-axis) partial stats over this block's 128 rows
    float* smax = (float*)&As[0][0];   // [2][128]
    float* ssum = smax + 256;
    const int rbase = bm * 128 + wm * 64 + fq * 4;
#pragma unroll
    for (int j = 0; j < 4; ++j) {
      const int col = bn * 128 + wn * 64 + j * 16 + fr;
      float m = -1e30f;
#pragma unroll
      for (int i = 0; i < 4; ++i)
#pragma unroll
        for (int r = 0; r < 4; ++r) {
          int row = rbase + i * 16 + r;
          float v = acc[i][j][r] * scale;
          m = (row >= col) ? fmaxf(m, v) : m;
        }
      m = fmaxf(m, __shfl_xor(m, 16));
      m = fmaxf(m, __shfl_xor(m, 32));
      float s = 0.f;
#pragma unroll
      for (int i = 0; i < 4; ++i)
#pragma unroll
        for (int r = 0; r < 4; ++r) {
          int row = rbase + i * 16 + r;
          float v = acc[i][j][r] * scale;
          s += (row >= col) ? __expf(v - m) : 0.f;
        }
      s += __shfl_xor(s, 16);
      s += __shfl_xor(s, 32);
      if (fq == 0) {
        smax[wm * 128 + wn * 64 + j * 16 + fr] = m;
        ssum[wm * 128 + wn * 64 + j * 16 + fr] = s;
      }
    }
    __syncthreads();
    if (tid < 128) {
      float m0 = smax[tid], m1 = smax[128 + tid];
      float s0 = ssum[tid], s1 = ssum[128 + tid];
      float M = fmaxf(m0, m1);
      float S2 = (m0 > -1e29f ? s0 * __expf(m0 - M) : 0.f)
               + (m1 > -1e29f ? s1 * __expf(m1 - M) : 0.f);
      long o = ((long)bz * 16 + bm) * 2048 + bn * 128 + tid;
      pm_out[o] = M;
      ps_out[o] = S2;
    }
  }
}

// combine 16 row-chunk partials per column; chunks < c/128 were never written.
__global__ void colstats_combine(const float* __restrict__ pmax, const float* __restrict__ psum,
                                 float* __restrict__ cmax, float* __restrict__ cinv) {
  const int bz = blockIdx.y;
  const int c = blockIdx.x * 256 + threadIdx.x;
  const int ch0 = c >> 7;
  float M = -1e30f;
  for (int ch = ch0; ch < 16; ++ch) M = fmaxf(M, pmax[((long)bz * 16 + ch) * 2048 + c]);
  float Ssum = 0.f;
  for (int ch = ch0; ch < 16; ++ch) {
    float m = pmax[((long)bz * 16 + ch) * 2048 + c];
    float s = psum[((long)bz * 16 + ch) * 2048 + c];
    Ssum += (m > -1e29f) ? s * __expf(m - M) : 0.f;
  }
  cmax[(long)bz * 2048 + c] = M;
  cinv[(long)bz * 2048 + c] = 1.f / Ssum;
}

// =====================================================================
// PV with fused softmax-normalize: out = P @ V where
// P[q][k] = (q>=k) ? exp(S[q][k]-M[k])*cinv[k] : 0, built on the fly
// during A-staging (reg-staged S -> exp/mask -> ds_write_b128, linear
// conflict-free). B (Vt) staged via global_load_lds. K capped (bm+1)*128.
// LPT: reversed bm so long-K blocks launch first.
// =====================================================================
struct SReg { f32x4 s0a, s0b, s1a, s1b, mA, mB, rA, rB; };

__global__ __launch_bounds__(256, 2) void pv_fused(
    const float* __restrict__ S, const float* __restrict__ cmax,
    const float* __restrict__ cinv, const short* __restrict__ Vt,
    float* __restrict__ out, long sS, long sO)
{
  const int bn = blockIdx.x;
  const int bm = (int)gridDim.y - 1 - (int)blockIdx.y;   // LPT order
  const int bz = blockIdx.z;
  const int NT = (bm + 1) * 4;                           // K-tiles of 32 (even)

  const float* Sb = S + (long)bz * sS;
  const float* Mb = cmax + (long)bz * 2048;
  const float* Rb = cinv + (long)bz * 2048;
  float* Cb = out + (long)bz * sO;

  __shared__ __align__(16) short As[2][4096];
  __shared__ __align__(16) short Bs[2][4096];

  const int tid = threadIdx.x;
  const int wid = tid >> 6, lane = tid & 63;
  const int wm = wid >> 1, wn = wid & 1;
  const int fr = lane & 15, fq = lane >> 4;
  const int fkB = fq * 16;

  // A-staging mapping: thread covers rows r0 and r0+64, 8 cols at cc
  const int r0 = tid >> 2;
  const int cc = (tid & 3) * 8;
  const int q0g = bm * 128 + r0;
  const int q1g = q0g + 64;
  const float* S0p = Sb + (long)q0g * 2048 + cc;
  const float* S1p = Sb + (long)q1g * 2048 + cc;
  const float* Mp = Mb + cc;
  const float* Rp = Rb + cc;

  // B staging (gload_lds), R2 pattern
  const int rC = lane >> 2, kB = (lane & 3) * 8;
  const short* Bb = Vt + (long)bz * 2048 + (long)(bn * 128 + rC) * 8192 + kB;

  auto STAGE_B = [&](int b, int t) {
#pragma unroll
    for (int j = 0; j < 2; ++j) {
      int chunk = j * 4 + wid;
      async16(&Bs[b][chunk * 512], Bb + (long)chunk * 16 * 8192 + t * 32);
    }
  };
  auto SLOAD = [&](SReg& R, int t) {
    int kk = t * 32;
    R.s0a = *(const f32x4*)(S0p + kk); R.s0b = *(const f32x4*)(S0p + kk + 4);
    R.s1a = *(const f32x4*)(S1p + kk); R.s1b = *(const f32x4*)(S1p + kk + 4);
    R.mA  = *(const f32x4*)(Mp  + kk); R.mB  = *(const f32x4*)(Mp  + kk + 4);
    R.rA  = *(const f32x4*)(Rp  + kk); R.rB  = *(const f32x4*)(Rp  + kk + 4);
  };

  f32x4 acc[4][4] = {};

  SReg Ra, Rb2;
  STAGE_B(0, 0); SLOAD(Ra, 0);          // 10 vmem ops in flight

  auto step = [&](SReg& R, SReg& Rn, int buf, int t) {
    if (t + 1 < NT) {
      STAGE_B(buf ^ 1, t + 1);
      SLOAD(Rn, t + 1);
      asm volatile("s_waitcnt vmcnt(10)" ::: "memory");  // t's 10 ops done
    } else {
      asm volatile("s_waitcnt vmcnt(0)" ::: "memory");
    }
    const int kk = t * 32;
    short8v w0, w1;
#pragma unroll
    for (int j = 0; j < 4; ++j) {
      int ka = kk + cc + j, kb2 = ka + 4;
      float e0 = __expf(R.s0a[j] - R.mA[j]) * R.rA[j];
      float e1 = __expf(R.s0b[j] - R.mB[j]) * R.rB[j];
      w0[j]     = (q0g >= ka)  ? (short)f2bf(e0) : (short)0;
      w0[4 + j] = (q0g >= kb2) ? (short)f2bf(e1) : (short)0;
      float e2 = __expf(R.s1a[j] - R.mA[j]) * R.rA[j];
      float e3 = __expf(R.s1b[j] - R.mB[j]) * R.rB[j];
      w1[j]     = (q1g >= ka)  ? (short)f2bf(e2) : (short)0;
      w1[4 + j] = (q1g >= kb2) ? (short)f2bf(e3) : (short)0;
    }
    *(short8v*)(&As[buf][r0 * 32 + cc]) = w0;          // linear, conflict-free
    *(short8v*)(&As[buf][(r0 + 64) * 32 + cc]) = w1;
    asm volatile("s_waitcnt lgkmcnt(0)" ::: "memory"); // own writes committed
    __builtin_amdgcn_s_barrier();                      // publish A writes + B glds
    __builtin_amdgcn_sched_barrier(0);

    bf16x8 af[4], bf_[4];
#pragma unroll
    for (int i = 0; i < 4; ++i)
      af[i] = *(const bf16x8*)((const char*)&As[buf][0] + (wm * 64 + i * 16 + fr) * 64 + fkB);
#pragma unroll
    for (int j = 0; j < 4; ++j)
      bf_[j] = *(const bf16x8*)((const char*)&Bs[buf][0] + (wn * 64 + j * 16 + fr) * 64 + fkB);
#pragma unroll
    for (int i = 0; i < 4; ++i)
#pragma unroll
      for (int j = 0; j < 4; ++j)
        acc[i][j] = __builtin_amdgcn_mfma_f32_16x16x32_bf16(af[i], bf_[j], acc[i][j], 0, 0, 0);
    __builtin_amdgcn_s_barrier();                      // reads done before next stage
  };

  for (int t = 0; t < NT; t += 2) { step(Ra, Rb2, 0, t); step(Rb2, Ra, 1, t + 1); }

#pragma unroll
  for (int i = 0; i < 4; ++i)
#pragma unroll
    for (int r = 0; r < 4; ++r) {
      int row = bm * 128 + wm * 64 + i * 16 + fq * 4 + r;
#pragma unroll
      for (int j = 0; j < 4; ++j) {
        int col = bn * 128 + wn * 64 + j * 16 + fr;
        Cb[(long)row * 1024 + col] = acc[i][j][r];
      }
    }
}

// ---------------- host side ----------------
extern "C" void kernel_launch(void* const* d_in, const int* in_sizes, int n_in,
                              void* d_out, int out_size, void* d_ws, size_t ws_size,
                              hipStream_t stream) {
  const float* x  = (const float*)d_in[0];
  const float* Wq = (const float*)d_in[1];
  const float* bq = (const float*)d_in[2];
  const float* Wk = (const float*)d_in[3];
  const float* bk = (const float*)d_in[4];
  const float* Wv = (const float*)d_in[5];
  const float* bv = (const float*)d_in[6];
  float* out = (float*)d_out;

  const size_t SZ_XB  = 8192ull * 1024 * 2;
  const size_t SZ_WQK = 2048ull * 1024 * 2;
  const size_t SZ_WT  = 1024ull * 1024 * 2;
  const size_t SZ_QK  = 8192ull * 2048 * 2;
  const size_t SZ_VT  = 1024ull * 8192 * 2;
  const size_t N_PMAX = 4ull * 16 * 2048;
  const size_t N_CMAX = 4ull * 2048;
  const size_t SZ_STATS = (N_PMAX * 2 + N_CMAX * 2 + 2048) * 4;
  const size_t SZ_S1 = 2048ull * 2048 * 4;

  char* p = (char*)d_ws;
  short* xb   = (short*)p; p += SZ_XB;
  short* wqkt = (short*)p; p += SZ_WQK;
  short* wvt  = (short*)p; p += SZ_WT;
  short* qkb  = (short*)p; p += SZ_QK;
  short* vt   = (short*)p; p += SZ_VT;
  float* pmax = (float*)p;
  float* psum = pmax + N_PMAX;
  float* cmax = psum + N_PMAX;
  float* cinv = cmax + N_CMAX;
  float* bqk  = cinv + N_CMAX;
  p += SZ_STATS;
  size_t fixed = (size_t)(p - (char*)d_ws);
  int nbuf = (ws_size >= fixed + 4 * SZ_S1) ? 4 : 1;
  float* S = (float*)p;

  cast_bf16_kernel<<<dim3(4096), dim3(256), 0, stream>>>(x, xb);
  transpose_cast_kernel<<<dim3(32, 32), dim3(256), 0, stream>>>(Wq, wqkt);
  transpose_cast_kernel<<<dim3(32, 32), dim3(256), 0, stream>>>(Wk, wqkt + 1024 * 1024);
  transpose_cast_kernel<<<dim3(32, 32), dim3(256), 0, stream>>>(Wv, wvt);
  concat2_kernel<<<dim3(8), dim3(256), 0, stream>>>(bq, bk, bqk);

  // QK fused projection: C[8192][2048] = xb @ [Wq;Wk]^T + [bq;bk]
  gemm_bt<short, 0><<<dim3(16, 64, 1), dim3(256), 0, stream>>>(
      xb, wqkt, qkb, 1024, 1024, 1024, 2048, 0L, 0L, 0L, nullptr, bqk, 1.f,
      nullptr, nullptr);
  // Vt[d][s] = Wv^T x^T + bv
  gemm_bt<short, 0><<<dim3(64, 8, 1), dim3(256), 0, stream>>>(
      wvt, xb, vt, 1024, 1024, 1024, 8192, 0L, 0L, 0L, bv, nullptr, 1.f,
      nullptr, nullptr);

  const long QKSTR = 2048L * 2048;
  const long SSTR  = 2048L * 2048;
  const long OSTR  = 2048L * 1024;

  for (int b0 = 0; b0 < 4; b0 += nbuf) {
    // scores + fused stats: compact lower-triangle grid (136 tiles/batch)
    gemm_bt<float, 1><<<dim3(136, 1, nbuf), dim3(256), 0, stream>>>(
        qkb + (long)b0 * QKSTR, qkb + (long)b0 * QKSTR + 1024, S,
        1024, 2048, 2048, 2048, QKSTR, QKSTR, SSTR,
        nullptr, nullptr, 0.03125f, pmax, psum);
    colstats_combine<<<dim3(8, nbuf), dim3(256), 0, stream>>>(pmax, psum, cmax, cinv);
    // attn = softmax-normalize(S) @ V, fused; K capped, LPT block order
    pv_fused<<<dim3(8, 16, nbuf), dim3(256), 0, stream>>>(
        S, cmax, cinv, vt + b0 * 2048, out + (long)b0 * OSTR, SSTR, OSTR);
  }
}

// Round 6
// 194.617 us; speedup vs baseline: 1.5615x; 1.2732x over previous
//
#include <hip/hip_runtime.h>

#define DEV __device__ __forceinline__

typedef float f32x4 __attribute__((ext_vector_type(4)));
typedef short short4v __attribute__((ext_vector_type(4)));
typedef short short8v __attribute__((ext_vector_type(8)));
typedef __bf16 bf16x8 __attribute__((ext_vector_type(8)));

#define QKSTR (2048L * 2048)
#define SSTR  (2048L * 2048)
#define OSTR  (2048L * 1024)

DEV unsigned short f2bf(float f) {
  unsigned int u = __float_as_uint(f);
  u += 0x7fffu + ((u >> 16) & 1u);   // round-to-nearest-even
  return (unsigned short)(u >> 16);
}

DEV void async16(void* lds, const void* g) {
  __builtin_amdgcn_global_load_lds((const __attribute__((address_space(1))) void*)g,
                                   (__attribute__((address_space(3))) void*)lds, 16, 0, 0);
}

DEV void store_elem(float* C, long i, float v) { C[i] = v; }
DEV void store_elem(short* C, long i, float v) { C[i] = (short)f2bf(v); }

// ---------------- fused prologue: cast x, transpose 3 W's, concat biases ----------------
__global__ void pre_kernel(const float* __restrict__ x, short* __restrict__ xb,
                           const float* __restrict__ Wq, const float* __restrict__ Wk,
                           const float* __restrict__ Wv, short* __restrict__ wqkt,
                           short* __restrict__ wvt,
                           const float* __restrict__ bq, const float* __restrict__ bk,
                           float* __restrict__ bqk)
{
  __shared__ float t[32][33];
  const int b = blockIdx.x;
  if (b < 4096) {                    // cast x -> bf16, 8 elems/thread
    long i = ((long)b * 256 + threadIdx.x) * 8;
    f32x4 a = *(const f32x4*)(x + i);
    f32x4 c = *(const f32x4*)(x + i + 4);
    short8v o;
#pragma unroll
    for (int j = 0; j < 4; ++j) { o[j] = (short)f2bf(a[j]); o[4 + j] = (short)f2bf(c[j]); }
    *(short8v*)(xb + i) = o;
  } else if (b < 7168) {             // transpose+cast one 32x32 tile of a W
    int tb = b - 4096;
    int which = tb >> 10;
    int t2 = tb & 1023;
    const float* W = (which == 0) ? Wq : (which == 1) ? Wk : Wv;
    short* Wt = (which == 0) ? wqkt : (which == 1) ? (wqkt + 1024 * 1024) : wvt;
    int n0 = (t2 & 31) * 32, k0 = (t2 >> 5) * 32;
    int tx = threadIdx.x & 31, ty = threadIdx.x >> 5;
#pragma unroll
    for (int r = 0; r < 32; r += 8) t[ty + r][tx] = W[(long)(k0 + ty + r) * 1024 + n0 + tx];
    __syncthreads();
#pragma unroll
    for (int r = 0; r < 32; r += 8)
      Wt[(long)(n0 + ty + r) * 1024 + k0 + tx] = (short)f2bf(t[tx][ty + r]);
  } else {                           // concat biases
    int i = (b - 7168) * 256 + threadIdx.x;
    bqk[i] = (i < 1024) ? bq[i] : bk[i - 1024];
  }
}

// ---------------- shared GEMM body (R2-proven): 128x128 tile, BK=32, dbuf+vmcnt(4) ----------------
// MODE: 0 plain; 1 = + fused column-stats epilogue; 2 = K capped at (bm+1)*128.
template <typename CT, int MODE>
DEV void gemm_body(short* As0, short* As1, short* Bs0, short* Bs1,
                   const short* A, const short* Bt, CT* C,
                   int K, int lda, int ldbt, int ldc,
                   const float* bias_m, const float* bias_n, float scale,
                   float* pm_out, float* ps_out, int bn, int bm, int bz)
{
  const int kend = (MODE == 2) ? min(K, (bm + 1) * 128) : K;

  const int tid = threadIdx.x;
  const int wid = tid >> 6, lane = tid & 63;
  const int wm = wid >> 1, wn = wid & 1;
  const int rC = lane >> 2;
  const int kB = (lane & 3) * 8;
  const int fr = lane & 15;
  const int fkB = (lane >> 4) * 16;

  const short* Ab = A + (long)bm * 128 * lda + (long)rC * lda + kB;
  const short* Bb = Bt + (long)bn * 128 * ldbt + (long)rC * ldbt + kB;

  f32x4 acc[4][4] = {};

  auto STAGE = [&](short* Asb, short* Bsb, int kk) {
#pragma unroll
    for (int j = 0; j < 2; ++j) {
      int chunk = j * 4 + wid;
      async16(&Asb[chunk * 512], Ab + (long)chunk * 16 * lda + kk);
      async16(&Bsb[chunk * 512], Bb + (long)chunk * 16 * ldbt + kk);
    }
  };

  STAGE(As0, Bs0, 0);
  int cur = 0;
  for (int kk = 0; kk < kend; kk += 32) {
    const short* Ac = cur ? As1 : As0;
    const short* Bc = cur ? Bs1 : Bs0;
    if (kk + 32 < kend) {
      STAGE(cur ? As0 : As1, cur ? Bs0 : Bs1, kk + 32);
      asm volatile("s_waitcnt vmcnt(4)" ::: "memory");
    } else {
      asm volatile("s_waitcnt vmcnt(0)" ::: "memory");
    }
    __builtin_amdgcn_s_barrier();
    __builtin_amdgcn_sched_barrier(0);

    bf16x8 af[4], bf_[4];
#pragma unroll
    for (int i = 0; i < 4; ++i)
      af[i] = *(const bf16x8*)((const char*)Ac + (wm * 64 + i * 16 + fr) * 64 + fkB);
#pragma unroll
    for (int j = 0; j < 4; ++j)
      bf_[j] = *(const bf16x8*)((const char*)Bc + (wn * 64 + j * 16 + fr) * 64 + fkB);
#pragma unroll
    for (int i = 0; i < 4; ++i)
#pragma unroll
      for (int j = 0; j < 4; ++j)
        acc[i][j] = __builtin_amdgcn_mfma_f32_16x16x32_bf16(af[i], bf_[j], acc[i][j], 0, 0, 0);
    __builtin_amdgcn_s_barrier();
    cur ^= 1;
  }

  const int fq = lane >> 4;
#pragma unroll
  for (int i = 0; i < 4; ++i) {
#pragma unroll
    for (int r = 0; r < 4; ++r) {
      int row = bm * 128 + wm * 64 + i * 16 + fq * 4 + r;
      float bmv = bias_m ? bias_m[row] : 0.f;
#pragma unroll
      for (int j = 0; j < 4; ++j) {
        int col = bn * 128 + wn * 64 + j * 16 + fr;
        float bnv = bias_n ? bias_n[col] : 0.f;
        store_elem(C, (long)row * ldc + col, acc[i][j][r] * scale + bmv + bnv);
      }
    }
  }

  if constexpr (MODE == 1) {
    // fused column (query-axis) partial stats over this block's 128 rows
    float* smax = (float*)As0;         // [2][128] scratch
    float* ssum = smax + 256;
    const int rbase = bm * 128 + wm * 64 + fq * 4;
#pragma unroll
    for (int j = 0; j < 4; ++j) {
      const int col = bn * 128 + wn * 64 + j * 16 + fr;
      float m = -1e30f;
#pragma unroll
      for (int i = 0; i < 4; ++i)
#pragma unroll
        for (int r = 0; r < 4; ++r) {
          int row = rbase + i * 16 + r;
          float v = acc[i][j][r] * scale;
          m = (row >= col) ? fmaxf(m, v) : m;
        }
      m = fmaxf(m, __shfl_xor(m, 16));
      m = fmaxf(m, __shfl_xor(m, 32));
      float s = 0.f;
#pragma unroll
      for (int i = 0; i < 4; ++i)
#pragma unroll
        for (int r = 0; r < 4; ++r) {
          int row = rbase + i * 16 + r;
          float v = acc[i][j][r] * scale;
          s += (row >= col) ? __expf(v - m) : 0.f;
        }
      s += __shfl_xor(s, 16);
      s += __shfl_xor(s, 32);
      if (fq == 0) {
        smax[wm * 128 + wn * 64 + j * 16 + fr] = m;
        ssum[wm * 128 + wn * 64 + j * 16 + fr] = s;
      }
    }
    __syncthreads();
    if (tid < 128) {
      float m0 = smax[tid], m1 = smax[128 + tid];
      float s0 = ssum[tid], s1 = ssum[128 + tid];
      float M = fmaxf(m0, m1);
      float S2 = (m0 > -1e29f ? s0 * __expf(m0 - M) : 0.f)
               + (m1 > -1e29f ? s1 * __expf(m1 - M) : 0.f);
      long o = ((long)bz * 16 + bm) * 2048 + bn * 128 + tid;
      pm_out[o] = M;
      ps_out[o] = S2;
    }
  }
}

// plain / PV wrapper. MODE 2 uses LPT ordering (long-K tiles first).
template <typename CT, int MODE>
__global__ __launch_bounds__(256, 2) void gemm_bt(
    const short* __restrict__ A, const short* __restrict__ Bt, CT* __restrict__ C,
    int K, int lda, int ldbt, int ldc,
    long sA, long sBt, long sC,
    const float* __restrict__ bias_m, const float* __restrict__ bias_n, float scale)
{
  __shared__ __align__(16) short lds[4][4096];
  const int bn = blockIdx.x;
  const int bm = (MODE == 2) ? ((int)gridDim.y - 1 - (int)blockIdx.y) : (int)blockIdx.y;
  const int bz = blockIdx.z;
  gemm_body<CT, MODE>(lds[0], lds[1], lds[2], lds[3],
                      A + (long)bz * sA, Bt + (long)bz * sBt, C + (long)bz * sC,
                      K, lda, ldbt, ldc, bias_m, bias_n, scale,
                      nullptr, nullptr, bn, bm, bz);
}

// fat dispatch: scores (compact lower-triangle, fused stats) + Vt projection.
// First ns blocks = scores (ns = 136*nz, nz batches, z0 = batch offset);
// remaining blocks (if any) = Vt tiles (64 bn x 8 bm).
__global__ __launch_bounds__(256, 2) void scores_vt(
    const short* __restrict__ qkb, float* __restrict__ S,
    const short* __restrict__ xb, const short* __restrict__ wvt,
    short* __restrict__ vt, const float* __restrict__ bv,
    float* __restrict__ pmax, float* __restrict__ psum, int ns, int z0)
{
  __shared__ __align__(16) short lds[4][4096];
  const int b = blockIdx.x;
  if (b < ns) {
    const int z = b / 136;               // local batch (indexes S, stats)
    int idx = b - z * 136;
    int bm = 0;
    while ((bm + 1) * (bm + 2) / 2 <= idx) ++bm;   // triangle decode, bn <= bm
    int bn = idx - bm * (bm + 1) / 2;
    const long qoff = (long)(z0 + z) * QKSTR;
    gemm_body<float, 1>(lds[0], lds[1], lds[2], lds[3],
                        qkb + qoff, qkb + qoff + 1024, S + (long)z * SSTR,
                        1024, 2048, 2048, 2048, nullptr, nullptr, 0.03125f,
                        pmax, psum, bn, bm, z);
  } else {
    const int b2 = b - ns;
    const int bn = b2 & 63, bm = b2 >> 6;
    gemm_body<short, 0>(lds[0], lds[1], lds[2], lds[3],
                        wvt, xb, vt, 1024, 1024, 1024, 8192,
                        bv, nullptr, 1.f, nullptr, nullptr, bn, bm, 0);
  }
}

// combine 16 row-chunk partials per column; chunks < c/128 were never written.
__global__ void colstats_combine(const float* __restrict__ pmax, const float* __restrict__ psum,
                                 float* __restrict__ cmax, float* __restrict__ cinv) {
  const int bz = blockIdx.y;
  const int c = blockIdx.x * 256 + threadIdx.x;
  const int ch0 = c >> 7;
  float M = -1e30f;
  for (int ch = ch0; ch < 16; ++ch) M = fmaxf(M, pmax[((long)bz * 16 + ch) * 2048 + c]);
  float Ssum = 0.f;
  for (int ch = ch0; ch < 16; ++ch) {
    float m = pmax[((long)bz * 16 + ch) * 2048 + c];
    float s = psum[((long)bz * 16 + ch) * 2048 + c];
    Ssum += (m > -1e29f) ? s * __expf(m - M) : 0.f;
  }
  cmax[(long)bz * 2048 + c] = M;
  cinv[(long)bz * 2048 + c] = 1.f / Ssum;
}

// P = (q>=c) ? exp(S-M[c])*Rinv[c] : 0 (bf16); only c < ((q>>7)+1)*128 is live.
__global__ void sm_normalize(const float* __restrict__ S, const float* __restrict__ cmax,
                             const float* __restrict__ cinv, short* __restrict__ P) {
  const int bz = blockIdx.y;
  const int q = blockIdx.x;
  const int climit = ((q >> 7) + 1) << 7;
  const float* Sr = S + ((long)bz * 2048 + q) * 2048;
  short* Pr = P + ((long)bz * 2048 + q) * 2048;
  const float* Mb = cmax + (long)bz * 2048;
  const float* Rb = cinv + (long)bz * 2048;
  for (int c = threadIdx.x * 4; c < climit; c += 1024) {
    f32x4 sv = *(const f32x4*)(Sr + c);
    f32x4 mv = *(const f32x4*)(Mb + c);
    f32x4 rv = *(const f32x4*)(Rb + c);
    short4v o;
#pragma unroll
    for (int j = 0; j < 4; ++j) {
      float p = (q >= c + j) ? __expf(sv[j] - mv[j]) * rv[j] : 0.f;
      o[j] = (short)f2bf(p);
    }
    *(short4v*)(Pr + c) = o;
  }
}

// ---------------- host side ----------------
extern "C" void kernel_launch(void* const* d_in, const int* in_sizes, int n_in,
                              void* d_out, int out_size, void* d_ws, size_t ws_size,
                              hipStream_t stream) {
  const float* x  = (const float*)d_in[0];
  const float* Wq = (const float*)d_in[1];
  const float* bq = (const float*)d_in[2];
  const float* Wk = (const float*)d_in[3];
  const float* bk = (const float*)d_in[4];
  const float* Wv = (const float*)d_in[5];
  const float* bv = (const float*)d_in[6];
  float* out = (float*)d_out;

  const size_t SZ_XB  = 8192ull * 1024 * 2;
  const size_t SZ_WQK = 2048ull * 1024 * 2;
  const size_t SZ_WT  = 1024ull * 1024 * 2;
  const size_t SZ_QK  = 8192ull * 2048 * 2;
  const size_t SZ_VT  = 1024ull * 8192 * 2;
  const size_t N_PMAX = 4ull * 16 * 2048;
  const size_t N_CMAX = 4ull * 2048;
  const size_t SZ_STATS = (N_PMAX * 2 + N_CMAX * 2 + 2048) * 4;
  const size_t SZ_S1 = 2048ull * 2048 * 4;
  const size_t SZ_P1 = 2048ull * 2048 * 2;

  char* p = (char*)d_ws;
  short* xb   = (short*)p; p += SZ_XB;
  short* wqkt = (short*)p; p += SZ_WQK;
  short* wvt  = (short*)p; p += SZ_WT;
  short* qkb  = (short*)p; p += SZ_QK;
  short* vt   = (short*)p; p += SZ_VT;
  float* pmax = (float*)p;
  float* psum = pmax + N_PMAX;
  float* cmax = psum + N_PMAX;
  float* cinv = cmax + N_CMAX;
  float* bqk  = cinv + N_CMAX;
  p += SZ_STATS;
  size_t fixed = (size_t)(p - (char*)d_ws);
  int nbuf = (ws_size >= fixed + 4 * (SZ_S1 + SZ_P1)) ? 4 : 1;
  float* S = (float*)p; p += (size_t)nbuf * SZ_S1;
  short* P = (short*)p;

  // 1) fused prologue (cast + 3 transposes + bias concat), one dispatch
  pre_kernel<<<dim3(7176), dim3(256), 0, stream>>>(x, xb, Wq, Wk, Wv, wqkt, wvt,
                                                   bq, bk, bqk);

  // 2) QK fused projection: C[8192][2048] = xb @ [Wq;Wk]^T + [bq;bk]
  gemm_bt<short, 0><<<dim3(16, 64, 1), dim3(256), 0, stream>>>(
      xb, wqkt, qkb, 1024, 1024, 1024, 2048, 0L, 0L, 0L, nullptr, bqk, 1.f);

  for (int b0 = 0; b0 < 4; b0 += nbuf) {
    const int nz = nbuf;
    const int ns = 136 * nz;
    // 3) scores (+fused stats) for nz batches, merged with Vt on first pass
    const int nvt = (b0 == 0) ? 512 : 0;
    scores_vt<<<dim3(ns + nvt), dim3(256), 0, stream>>>(
        qkb, S, xb, wvt, vt, bv, pmax, psum, ns, b0);
    // 4) column softmax over q
    colstats_combine<<<dim3(8, nz), dim3(256), 0, stream>>>(pmax, psum, cmax, cinv);
    sm_normalize<<<dim3(2048, nz), dim3(256), 0, stream>>>(S, cmax, cinv, P);
    // 5) attn = P @ V, K capped per q-tile, LPT block order
    gemm_bt<float, 2><<<dim3(8, 16, nz), dim3(256), 0, stream>>>(
        P, vt + b0 * 2048, out + (long)b0 * OSTR, 2048, 2048, 8192, 1024,
        SSTR, 2048L, OSTR, nullptr, nullptr, 1.f);
  }
}